// Round 13
// baseline (114.059 us; speedup 1.0000x reference)
//
#include <hip/hip_runtime.h>

#define LENSZ 11
#define RAD   5
#define TSX   128           // tile width  (8 px per thread in x)
#define TSY   16            // tile height
#define WINX  (TSX + LENSZ - 1)   // 138
#define WINY  (TSY + LENSZ - 1)   // 26
#define RS    140           // f16 plane row stride (halves)
#define RS_E  72            // Es parity-plane row stride (floats)
#define NPAIR 69            // WINX/2 staging pairs per row
#define IMG_H 1024
#define IMG_W 1024
#define HW    (IMG_H * IMG_W)

// sigmoid(4*(sd-dd)) = 1/(1 + Es(s)/Es(d)), Es = exp2(C4L2*disp)
// C4L2 = -4*log2(e). |disp| <= ~10.4 => Es in [2^-60, 2^60], f32-safe.
#define C4L2  (-5.770780163555854f)
#define DEADC (-3000.0f)    // dead-offset c0: clamp(coc+c0)==0

// NOTE: cvt_pkrtz returns __fp16 ext_vector(2), not _Float16 (R8 lesson).
// NOTE: 64-bit-operand VOP3P f32 asm (v_pk_*_f32) produced garbage twice
// (R6 NaN, R11 absmax 987) — do not use. 32-bit-operand asm (v_dot2) is OK.
typedef __fp16 v2h __attribute__((ext_vector_type(2)));

// Forced single-instruction packed MAC: acc += a.lo*b.lo + a.hi*b.hi.
__device__ __forceinline__ float dot2acc(float acc, v2h a, v2h b) {
    asm("v_dot2_f32_f16 %0, %1, %2, %0" : "+v"(acc) : "v"(a), "v"(b));
    return acc;
}

// c0 = 0.5 - dist(dy,dx), literal table (R3 lesson: no iterative constexpr
// math on hot paths). Out-of-disk (n>30) -> DEADC so clamp gives exact 0;
// also drives compile-time pruning of fully-dead units after unrolling.
constexpr float C0V(int dy, int dx) {
    switch (dy * dy + dx * dx) {
        case 0:  return  0.5f;
        case 1:  return -0.5f;
        case 2:  return -0.914213562f;
        case 4:  return -1.5f;
        case 5:  return -1.736067977f;
        case 8:  return -2.328427125f;
        case 9:  return -2.5f;
        case 10: return -2.662277660f;
        case 13: return -3.105551275f;
        case 16: return -3.5f;
        case 17: return -3.623105626f;
        case 18: return -3.742640687f;
        case 20: return -3.972135955f;
        case 25: return -4.5f;
        case 26: return -4.599019514f;
        case 29: return -4.885164807f;
        default: return DEADC;
    }
}

// Source-only quantities staged per window pixel (R13: exp2/coc hoisted out
// of the inner loop). Es parity-split (even/odd cols) -> 16B lane stride on
// b32 reads = 2-way bank aliasing = free (R12's float2 read was 4-way).
__shared__ __align__(16) float  esE[WINY * RS_E];    // Es, even cols, f32
__shared__ __align__(16) float  esO[WINY * RS_E];    // Es, odd cols,  f32
__shared__ __align__(8)  __fp16 ccp[WINY * RS];      // coc, f16
__shared__ __align__(8)  __fp16 rpl[WINY * RS];      // r, f16
__shared__ __align__(8)  __fp16 gpl[WINY * RS];      // g, f16
__shared__ __align__(8)  __fp16 bpl[WINY * RS];      // b, f16

// One window row at runtime y-index `wy`, compile-time |dy| and disk bounds.
// Per src-pair: 6 LDS reads, zero prep VALU. rcp shared across the src pair;
// w0/w packed f16; accumulate via forced v_dot2_f32_f16.
template<int ADY, int XMN, int XMX>
__device__ __forceinline__ void do_row(
    int wy, int x8, const float (&G)[8], v2h one2,
    float (&nr)[8], float (&ng)[8], float (&nb)[8], float (&dn)[8])
{
    const v2h zero2 = {(__fp16)0.f, (__fp16)0.f};
    const v2h onee2 = {(__fp16)1.f, (__fp16)1.f};
#pragma unroll
    for (int kxe = (XMN & ~1); kxe <= XMX + 7; kxe += 2) {
        const int xo = x8 + kxe;                 // even
        const int xh = xo >> 1;
        const float Ea = esE[wy * RS_E + xh];
        const float Eb = esO[wy * RS_E + xh];
        const v2h coc2 = *reinterpret_cast<const v2h*>(&ccp[wy * RS + xo]);
        const v2h r2 = *reinterpret_cast<const v2h*>(&rpl[wy * RS + xo]);
        const v2h g2 = *reinterpret_cast<const v2h*>(&gpl[wy * RS + xo]);
        const v2h b2 = *reinterpret_cast<const v2h*>(&bpl[wy * RS + xo]);
#pragma unroll
        for (int j = 0; j < 8; ++j) {
            const float c0a = C0V(ADY, kxe - j - RAD);
            const float c0b = C0V(ADY, kxe + 1 - j - RAD);
            if (c0a == DEADC && c0b == DEADC) continue;   // folds post-unroll
            const float fa = fmaf(Ea, G[j], 1.f);
            const float fb = fmaf(Eb, G[j], 1.f);
            const float rr = __builtin_amdgcn_rcpf(fa * fb);
            const v2h occ2 = __builtin_amdgcn_cvt_pkrtz(rr * fb, rr * fa);
            const v2h c0h = {(__fp16)c0a, (__fp16)c0b};
            v2h t = coc2 + c0h;                          // v_pk_add_f16
            t = __builtin_elementwise_max(t, zero2);     // v_pk_max_f16
            t = __builtin_elementwise_min(t, onee2);     // v_pk_min_f16
            const v2h wh = t * occ2;                     // v_pk_mul_f16
            nr[j] = dot2acc(nr[j], wh, r2);
            ng[j] = dot2acc(ng[j], wh, g2);
            nb[j] = dot2acc(nb[j], wh, b2);
            dn[j] = dot2acc(dn[j], wh, one2);
        }
    }
}

__global__ __launch_bounds__(256, 4) void scatter_render_kernel(
    const float* __restrict__ x,      // (B,4,H,W)
    const float* __restrict__ lens,   // (B,1)
    float* __restrict__ out)          // (B,3,H,W)
{
    const int b   = blockIdx.z;
    const int bx0 = blockIdx.x * TSX;
    const int by0 = blockIdx.y * TSY;
    const int tx  = threadIdx.x;      // 0..15
    const int ty  = threadIdx.y;      // 0..15
    const int tid = ty * 16 + tx;

    const float scale = lens[b];
    const float* xb = x + (size_t)b * 4 * HW;

    // ---- stage window: rgb/coc f16, Es f32 parity-split (all source-only
    // math done once here: 2 exp2 + 2 fabs-mul per pair vs per-use in-loop)
    for (int p = tid; p < WINY * NPAIR; p += 256) {
        int wy = p / NPAIR;
        int px = (p - wy * NPAIR) * 2;
        int gy = by0 - RAD + wy;  gy = min(max(gy, 0), IMG_H - 1);
        int g0 = bx0 - RAD + px;      g0 = min(max(g0, 0), IMG_W - 1);
        int g1 = bx0 - RAD + px + 1;  g1 = min(max(g1, 0), IMG_W - 1);
        int ba = gy * IMG_W + g0;
        int bb = gy * IMG_W + g1;
        float r0 = xb[ba],          r1 = xb[bb];
        float q0 = xb[ba + HW],     q1 = xb[bb + HW];
        float s0 = xb[ba + 2 * HW], s1 = xb[bb + 2 * HW];
        float d0 = xb[ba + 3 * HW], d1 = xb[bb + 3 * HW];
        int oh = wy * RS + px;
        *reinterpret_cast<v2h*>(&rpl[oh]) = __builtin_amdgcn_cvt_pkrtz(r0, r1);
        *reinterpret_cast<v2h*>(&gpl[oh]) = __builtin_amdgcn_cvt_pkrtz(q0, q1);
        *reinterpret_cast<v2h*>(&bpl[oh]) = __builtin_amdgcn_cvt_pkrtz(s0, s1);
        *reinterpret_cast<v2h*>(&ccp[oh]) =
            __builtin_amdgcn_cvt_pkrtz(scale * fabsf(d0), scale * fabsf(d1));
        int oe = wy * RS_E + (px >> 1);
        esE[oe] = __builtin_amdgcn_exp2f(C4L2 * d0);
        esO[oe] = __builtin_amdgcn_exp2f(C4L2 * d1);
    }
    __syncthreads();

    // per-dest occlusion gate: G_j = exp2(-C4L2*dd_j) = 1/Es(dest_j)
    const int x8 = 8 * tx;
    float G[8];
#pragma unroll
    for (int j = 0; j < 8; ++j) {
        const int cc = x8 + j + RAD;
        const float esd = (cc & 1) ? esO[(ty + RAD) * RS_E + (cc >> 1)]
                                   : esE[(ty + RAD) * RS_E + (cc >> 1)];
        G[j] = __builtin_amdgcn_rcpf(esd);
    }
    v2h one2; one2.x = (__fp16)1.f; one2.y = (__fp16)1.f;

    float nr[8] = {0.f, 0.f, 0.f, 0.f, 0.f, 0.f, 0.f, 0.f};
    float ng[8] = {0.f, 0.f, 0.f, 0.f, 0.f, 0.f, 0.f, 0.f};
    float nb[8] = {0.f, 0.f, 0.f, 0.f, 0.f, 0.f, 0.f, 0.f};
    float dn[8] = {0.f, 0.f, 0.f, 0.f, 0.f, 0.f, 0.f, 0.f};

    // mirrored row pairs share |dy| -> c0 compile-time; runtime 2-trip loops
    // keep live ranges bounded (R1's full unroll spilled).
#pragma unroll 1
    for (int t = 0; t < 2; ++t)
        do_row<5, 3, 7>(ty + t * 10, x8, G, one2, nr, ng, nb, dn);
#pragma unroll 1
    for (int t = 0; t < 2; ++t)
        do_row<4, 2, 8>(ty + 1 + t * 8, x8, G, one2, nr, ng, nb, dn);
#pragma unroll 1
    for (int t = 0; t < 2; ++t)
        do_row<3, 1, 9>(ty + 2 + t * 6, x8, G, one2, nr, ng, nb, dn);
#pragma unroll 1
    for (int t = 0; t < 2; ++t)
        do_row<2, 0, 10>(ty + 3 + t * 4, x8, G, one2, nr, ng, nb, dn);
#pragma unroll 1
    for (int t = 0; t < 2; ++t)
        do_row<1, 0, 10>(ty + 4 + t * 2, x8, G, one2, nr, ng, nb, dn);
    do_row<0, 0, 10>(ty + 5, x8, G, one2, nr, ng, nb, dn);

    // epilogue: 8 consecutive pixels -> 2x float4 stores per channel
    const size_t obase = (size_t)b * 3 * HW + (size_t)(by0 + ty) * IMG_W + (bx0 + x8);

    float inv[8];
#pragma unroll
    for (int j = 0; j < 8; ++j)
        inv[j] = __builtin_amdgcn_rcpf(dn[j] + 1e-8f);

#pragma unroll
    for (int h = 0; h < 2; ++h) {
        const int o4 = 4 * h;
        float4 o;
        o.x = nr[o4+0]*inv[o4+0]; o.y = nr[o4+1]*inv[o4+1];
        o.z = nr[o4+2]*inv[o4+2]; o.w = nr[o4+3]*inv[o4+3];
        *reinterpret_cast<float4*>(&out[obase + o4]) = o;
        o.x = ng[o4+0]*inv[o4+0]; o.y = ng[o4+1]*inv[o4+1];
        o.z = ng[o4+2]*inv[o4+2]; o.w = ng[o4+3]*inv[o4+3];
        *reinterpret_cast<float4*>(&out[obase + HW + o4]) = o;
        o.x = nb[o4+0]*inv[o4+0]; o.y = nb[o4+1]*inv[o4+1];
        o.z = nb[o4+2]*inv[o4+2]; o.w = nb[o4+3]*inv[o4+3];
        *reinterpret_cast<float4*>(&out[obase + 2 * HW + o4]) = o;
    }
}

extern "C" void kernel_launch(void* const* d_in, const int* in_sizes, int n_in,
                              void* d_out, int out_size, void* d_ws, size_t ws_size,
                              hipStream_t stream) {
    const float* x    = (const float*)d_in[0];
    const float* lens = (const float*)d_in[1];
    float* out        = (float*)d_out;

    const int B = in_sizes[1];  // lens_effects has B elements

    dim3 block(16, 16, 1);
    dim3 grid(IMG_W / TSX, IMG_H / TSY, B);
    scatter_render_kernel<<<grid, block, 0, stream>>>(x, lens, out);
}

// Round 14
// 101.110 us; speedup vs baseline: 1.1281x; 1.1281x over previous
//
#include <hip/hip_runtime.h>

#define LENSZ 11
#define RAD   5
#define TSX   128           // tile width  (8 px per thread in x)
#define TSY   16            // tile height
#define WINX  (TSX + LENSZ - 1)   // 138
#define WINY  (TSY + LENSZ - 1)   // 26
#define NPAIR 69            // source-pair slots per window row
#define PKS   70            // pk plane row stride (uint4 slots)
#define ESS   70            // es plane row stride (u32 slots)
#define IMG_H 1024
#define IMG_W 1024
#define HW    (IMG_H * IMG_W)

// sigmoid(4*(sd-dd)) = 1/(1 + Es(s)/Es(d)), Es = exp2(C4L2*disp)
// C4L2 = -4*log2(e). |disp| <= ~10.4 => Es in [2^-60, 2^60]; bf16 storage
// keeps the range, 0.4% rel err -> ~0.008 output err, threshold 0.02.
#define C4L2  (-5.770780163555854f)
#define DEADC (-3000.0f)    // dead-offset c0: clamp(coc+c0)==0

// NOTE: cvt_pkrtz returns __fp16 ext_vector(2), not _Float16 (R8 lesson).
// NOTE: 64-bit-operand VOP3P f32 asm produced garbage twice (R6, R11) — do
// not use. 32-bit-operand asm (v_dot2_f32_f16) is verified OK (R10).
typedef __fp16 v2h __attribute__((ext_vector_type(2)));

// Forced single-instruction packed MAC: acc += a.lo*b.lo + a.hi*b.hi.
__device__ __forceinline__ float dot2acc(float acc, v2h a, v2h b) {
    asm("v_dot2_f32_f16 %0, %1, %2, %0" : "+v"(acc) : "v"(a), "v"(b));
    return acc;
}

// c0 = 0.5 - dist(dy,dx), literal table (R3 lesson: no iterative constexpr
// math on hot paths). Out-of-disk (n>30) -> DEADC so clamp gives exact 0;
// also drives compile-time pruning of fully-dead units after unrolling.
constexpr float C0V(int dy, int dx) {
    switch (dy * dy + dx * dx) {
        case 0:  return  0.5f;
        case 1:  return -0.5f;
        case 2:  return -0.914213562f;
        case 4:  return -1.5f;
        case 5:  return -1.736067977f;
        case 8:  return -2.328427125f;
        case 9:  return -2.5f;
        case 10: return -2.662277660f;
        case 13: return -3.105551275f;
        case 16: return -3.5f;
        case 17: return -3.623105626f;
        case 18: return -3.742640687f;
        case 20: return -3.972135955f;
        case 25: return -4.5f;
        case 26: return -4.599019514f;
        case 29: return -4.885164807f;
        default: return DEADC;
    }
}

// pk slot XOR swizzle: lane slot-stride is 4 (16B slots) -> naive 8-way bank
// conflict; phys = s ^ ((s>>3)&7) spreads 16 lanes 2-per-bank-group (free).
__device__ __forceinline__ int pswz(int s) { return s ^ ((s >> 3) & 7); }

// Packed per-source-pair data: {coc2(f16x2), r2, g2, b2} + Es as bf16 pair.
__shared__ __align__(16) uint4    pk[WINY * PKS];
__shared__ __align__(16) unsigned es[WINY * ESS];

// One window row at runtime y-index `wy`, compile-time |dy| and disk bounds.
// Per src-pair: 1x ds_read_b128 + 1x ds_read_b32, 2 VALU unpack. rcp shared
// across the src pair; w0/w packed f16; accumulate via forced v_dot2_f32_f16.
template<int ADY, int XMN, int XMX>
__device__ __forceinline__ void do_row(
    int wy, int tx4, const float (&G)[8], v2h one2,
    float (&nr)[8], float (&ng)[8], float (&nb)[8], float (&dn)[8])
{
    const v2h zero2 = {(__fp16)0.f, (__fp16)0.f};
    const v2h onee2 = {(__fp16)1.f, (__fp16)1.f};
#pragma unroll
    for (int kxe = (XMN & ~1); kxe <= XMX + 7; kxe += 2) {
        const int s = tx4 + (kxe >> 1);            // logical pair slot
        const uint4 q = pk[wy * PKS + pswz(s)];
        const v2h coc2 = *reinterpret_cast<const v2h*>(&q.x);
        const v2h r2   = *reinterpret_cast<const v2h*>(&q.y);
        const v2h g2   = *reinterpret_cast<const v2h*>(&q.z);
        const v2h b2   = *reinterpret_cast<const v2h*>(&q.w);
        const unsigned ue = es[wy * ESS + s];
        const float Ea = __uint_as_float(ue << 16);
        const float Eb = __uint_as_float(ue & 0xffff0000u);
#pragma unroll
        for (int j = 0; j < 8; ++j) {
            const float c0a = C0V(ADY, kxe - j - RAD);
            const float c0b = C0V(ADY, kxe + 1 - j - RAD);
            if (c0a == DEADC && c0b == DEADC) continue;   // folds post-unroll
            const float fa = fmaf(Ea, G[j], 1.f);
            const float fb = fmaf(Eb, G[j], 1.f);
            const float rr = __builtin_amdgcn_rcpf(fa * fb);
            const v2h occ2 = __builtin_amdgcn_cvt_pkrtz(rr * fb, rr * fa);
            const v2h c0h = {(__fp16)c0a, (__fp16)c0b};
            v2h t = coc2 + c0h;                          // v_pk_add_f16
            t = __builtin_elementwise_max(t, zero2);     // v_pk_max_f16
            t = __builtin_elementwise_min(t, onee2);     // v_pk_min_f16
            const v2h wh = t * occ2;                     // v_pk_mul_f16
            nr[j] = dot2acc(nr[j], wh, r2);
            ng[j] = dot2acc(ng[j], wh, g2);
            nb[j] = dot2acc(nb[j], wh, b2);
            dn[j] = dot2acc(dn[j], wh, one2);
        }
    }
}

__global__ __launch_bounds__(256, 4) void scatter_render_kernel(
    const float* __restrict__ x,      // (B,4,H,W)
    const float* __restrict__ lens,   // (B,1)
    float* __restrict__ out)          // (B,3,H,W)
{
    const int b   = blockIdx.z;
    const int bx0 = blockIdx.x * TSX;
    const int by0 = blockIdx.y * TSY;
    const int tx  = threadIdx.x;      // 0..15
    const int ty  = threadIdx.y;      // 0..15
    const int tid = ty * 16 + tx;

    const float scale = lens[b];
    const float* xb = x + (size_t)b * 4 * HW;

    // ---- stage window: all source-only math done once here (coc, Es);
    // pack {coc2,r2,g2,b2} into a swizzled uint4 slot + Es as bf16-RN pair.
    for (int p = tid; p < WINY * NPAIR; p += 256) {
        int wy = p / NPAIR;
        int sl = p - wy * NPAIR;
        int px = sl * 2;
        int gy = by0 - RAD + wy;  gy = min(max(gy, 0), IMG_H - 1);
        int g0 = bx0 - RAD + px;      g0 = min(max(g0, 0), IMG_W - 1);
        int g1 = bx0 - RAD + px + 1;  g1 = min(max(g1, 0), IMG_W - 1);
        int ba = gy * IMG_W + g0;
        int bb = gy * IMG_W + g1;
        float r0 = xb[ba],          r1 = xb[bb];
        float q0 = xb[ba + HW],     q1 = xb[bb + HW];
        float s0 = xb[ba + 2 * HW], s1 = xb[bb + 2 * HW];
        float d0 = xb[ba + 3 * HW], d1 = xb[bb + 3 * HW];
        uint4 q;
        v2h h;
        h = __builtin_amdgcn_cvt_pkrtz(scale * fabsf(d0), scale * fabsf(d1));
        q.x = *reinterpret_cast<unsigned*>(&h);
        h = __builtin_amdgcn_cvt_pkrtz(r0, r1);
        q.y = *reinterpret_cast<unsigned*>(&h);
        h = __builtin_amdgcn_cvt_pkrtz(q0, q1);
        q.z = *reinterpret_cast<unsigned*>(&h);
        h = __builtin_amdgcn_cvt_pkrtz(s0, s1);
        q.w = *reinterpret_cast<unsigned*>(&h);
        pk[wy * PKS + pswz(sl)] = q;
        // Es pair as round-to-nearest bf16 halves of one u32
        float Ea = __builtin_amdgcn_exp2f(C4L2 * d0);
        float Eb = __builtin_amdgcn_exp2f(C4L2 * d1);
        unsigned ua = (__float_as_uint(Ea) + 0x8000u) >> 16;
        unsigned ub = (__float_as_uint(Eb) + 0x8000u) & 0xffff0000u;
        es[wy * ESS + sl] = ua | ub;
    }
    __syncthreads();

    // per-dest occlusion gate: G_j = 1/Es(dest_j) from the SAME stored bf16
    // value dest reads as source -> self-occlusion exactly 0.5, den >= 0.25.
    const int x8 = 8 * tx;
    float G[8];
#pragma unroll
    for (int j = 0; j < 8; ++j) {
        const int cc = x8 + j + RAD;
        const unsigned ue = es[(ty + RAD) * ESS + (cc >> 1)];
        const float esd = (cc & 1) ? __uint_as_float(ue & 0xffff0000u)
                                   : __uint_as_float(ue << 16);
        G[j] = __builtin_amdgcn_rcpf(esd);
    }
    v2h one2; one2.x = (__fp16)1.f; one2.y = (__fp16)1.f;

    float nr[8] = {0.f, 0.f, 0.f, 0.f, 0.f, 0.f, 0.f, 0.f};
    float ng[8] = {0.f, 0.f, 0.f, 0.f, 0.f, 0.f, 0.f, 0.f};
    float nb[8] = {0.f, 0.f, 0.f, 0.f, 0.f, 0.f, 0.f, 0.f};
    float dn[8] = {0.f, 0.f, 0.f, 0.f, 0.f, 0.f, 0.f, 0.f};

    const int tx4 = 4 * tx;
    // mirrored row pairs share |dy| -> c0 compile-time; runtime 2-trip loops
    // keep live ranges bounded (R1's full unroll spilled).
#pragma unroll 1
    for (int t = 0; t < 2; ++t)
        do_row<5, 3, 7>(ty + t * 10, tx4, G, one2, nr, ng, nb, dn);
#pragma unroll 1
    for (int t = 0; t < 2; ++t)
        do_row<4, 2, 8>(ty + 1 + t * 8, tx4, G, one2, nr, ng, nb, dn);
#pragma unroll 1
    for (int t = 0; t < 2; ++t)
        do_row<3, 1, 9>(ty + 2 + t * 6, tx4, G, one2, nr, ng, nb, dn);
#pragma unroll 1
    for (int t = 0; t < 2; ++t)
        do_row<2, 0, 10>(ty + 3 + t * 4, tx4, G, one2, nr, ng, nb, dn);
#pragma unroll 1
    for (int t = 0; t < 2; ++t)
        do_row<1, 0, 10>(ty + 4 + t * 2, tx4, G, one2, nr, ng, nb, dn);
    do_row<0, 0, 10>(ty + 5, tx4, G, one2, nr, ng, nb, dn);

    // epilogue: 8 consecutive pixels -> 2x float4 stores per channel
    const size_t obase = (size_t)b * 3 * HW + (size_t)(by0 + ty) * IMG_W + (bx0 + x8);

    float inv[8];
#pragma unroll
    for (int j = 0; j < 8; ++j)
        inv[j] = __builtin_amdgcn_rcpf(dn[j] + 1e-8f);

#pragma unroll
    for (int h = 0; h < 2; ++h) {
        const int o4 = 4 * h;
        float4 o;
        o.x = nr[o4+0]*inv[o4+0]; o.y = nr[o4+1]*inv[o4+1];
        o.z = nr[o4+2]*inv[o4+2]; o.w = nr[o4+3]*inv[o4+3];
        *reinterpret_cast<float4*>(&out[obase + o4]) = o;
        o.x = ng[o4+0]*inv[o4+0]; o.y = ng[o4+1]*inv[o4+1];
        o.z = ng[o4+2]*inv[o4+2]; o.w = ng[o4+3]*inv[o4+3];
        *reinterpret_cast<float4*>(&out[obase + HW + o4]) = o;
        o.x = nb[o4+0]*inv[o4+0]; o.y = nb[o4+1]*inv[o4+1];
        o.z = nb[o4+2]*inv[o4+2]; o.w = nb[o4+3]*inv[o4+3];
        *reinterpret_cast<float4*>(&out[obase + 2 * HW + o4]) = o;
    }
}

extern "C" void kernel_launch(void* const* d_in, const int* in_sizes, int n_in,
                              void* d_out, int out_size, void* d_ws, size_t ws_size,
                              hipStream_t stream) {
    const float* x    = (const float*)d_in[0];
    const float* lens = (const float*)d_in[1];
    float* out        = (float*)d_out;

    const int B = in_sizes[1];  // lens_effects has B elements

    dim3 block(16, 16, 1);
    dim3 grid(IMG_W / TSX, IMG_H / TSY, B);
    scatter_render_kernel<<<grid, block, 0, stream>>>(x, lens, out);
}

// Round 15
// 96.784 us; speedup vs baseline: 1.1785x; 1.0447x over previous
//
#include <hip/hip_runtime.h>

#define LENSZ 11
#define RAD   5
#define TSX   128           // tile width  (8 px per thread in x)
#define TSY   16            // tile height
#define WINX  (TSX + LENSZ - 1)   // 138
#define WINY  (TSY + LENSZ - 1)   // 26
#define NPAIR 69            // source-pair slots per window row
#define PKS   70            // pk plane row stride (uint4 slots)
#define ESS   71            // es plane row stride (u32) — 71 mod 32 = 7 puts
                            // the wave's 4 ty-rows in 4 disjoint bank-cosets
                            // (70 = 6 mod 32 collided rows 0&2 -> 4-way)
#define IMG_H 1024
#define IMG_W 1024
#define HW    (IMG_H * IMG_W)

// sigmoid(4*(sd-dd)) = 1/(1 + Es(s)/Es(d)), Es = exp2(C4L2*disp)
// C4L2 = -4*log2(e). |disp| <= ~10.4 => Es in [2^-60, 2^60]; bf16 storage
// keeps the range, 0.4% rel err -> ~0.008 output err, threshold 0.02.
#define C4L2  (-5.770780163555854f)
#define DEADC (-3000.0f)    // dead-offset c0: clamp(coc+c0)==0

// NOTE: cvt_pkrtz returns __fp16 ext_vector(2), not _Float16 (R8 lesson).
// NOTE: 64-bit-operand VOP3P f32 asm produced garbage (R6, R11) and the
// VOP3P clamp modifier is implicated by R11's DEADC-leak signature (absmax
// ~987 = unclamped -3000*occ*color) — both stay condemned. 32-bit-operand
// v_dot2_f32_f16 asm is verified OK (R10: -4 us, correct).
typedef __fp16 v2h __attribute__((ext_vector_type(2)));

// Forced single-instruction packed MAC: acc += a.lo*b.lo + a.hi*b.hi.
__device__ __forceinline__ float dot2acc(float acc, v2h a, v2h b) {
    asm("v_dot2_f32_f16 %0, %1, %2, %0" : "+v"(acc) : "v"(a), "v"(b));
    return acc;
}

// c0 = 0.5 - dist(dy,dx), literal table (R3 lesson: no iterative constexpr
// math on hot paths). Out-of-disk (n>30) -> DEADC so clamp gives exact 0;
// also drives compile-time pruning / half-dead fast path after unrolling.
constexpr float C0V(int dy, int dx) {
    switch (dy * dy + dx * dx) {
        case 0:  return  0.5f;
        case 1:  return -0.5f;
        case 2:  return -0.914213562f;
        case 4:  return -1.5f;
        case 5:  return -1.736067977f;
        case 8:  return -2.328427125f;
        case 9:  return -2.5f;
        case 10: return -2.662277660f;
        case 13: return -3.105551275f;
        case 16: return -3.5f;
        case 17: return -3.623105626f;
        case 18: return -3.742640687f;
        case 20: return -3.972135955f;
        case 25: return -4.5f;
        case 26: return -4.599019514f;
        case 29: return -4.885164807f;
        default: return DEADC;
    }
}

// pk slot XOR swizzle: lane slot-stride is 4 (16B slots) -> naive 8-way bank
// conflict; phys = s ^ ((s>>3)&7) spreads 16 lanes 2-per-bank-group (free).
__device__ __forceinline__ int pswz(int s) { return s ^ ((s >> 3) & 7); }

// Packed per-source-pair data: {coc2(f16x2), r2, g2, b2} + Es as bf16 pair.
__shared__ __align__(16) uint4    pk[WINY * PKS];
__shared__ __align__(16) unsigned es[WINY * ESS];

// One window row at runtime y-index `wy`, compile-time |dy| and disk bounds.
// Per src-pair: 1x ds_read_b128 + 1x ds_read_b32, 2 VALU unpack. rcp shared
// across the src pair; w0/w packed f16; accumulate via forced v_dot2_f32_f16.
// Half-dead units (one side out-of-disk) take a cheaper scalar-occ path; the
// dead half's weight is zeroed by the DEADC clamp either way.
template<int ADY, int XMN, int XMX>
__device__ __forceinline__ void do_row(
    int wy, int tx4, const float (&G)[8], v2h one2,
    float (&nr)[8], float (&ng)[8], float (&nb)[8], float (&dn)[8])
{
    const v2h zero2 = {(__fp16)0.f, (__fp16)0.f};
    const v2h onee2 = {(__fp16)1.f, (__fp16)1.f};
#pragma unroll
    for (int kxe = (XMN & ~1); kxe <= XMX + 7; kxe += 2) {
        const int s = tx4 + (kxe >> 1);            // logical pair slot
        const uint4 q = pk[wy * PKS + pswz(s)];
        const v2h coc2 = *reinterpret_cast<const v2h*>(&q.x);
        const v2h r2   = *reinterpret_cast<const v2h*>(&q.y);
        const v2h g2   = *reinterpret_cast<const v2h*>(&q.z);
        const v2h b2   = *reinterpret_cast<const v2h*>(&q.w);
        const unsigned ue = es[wy * ESS + s];
        const float Ea = __uint_as_float(ue << 16);
        const float Eb = __uint_as_float(ue & 0xffff0000u);
#pragma unroll
        for (int j = 0; j < 8; ++j) {
            const float c0a = C0V(ADY, kxe - j - RAD);
            const float c0b = C0V(ADY, kxe + 1 - j - RAD);
            if (c0a == DEADC && c0b == DEADC) continue;   // folds post-unroll
            v2h occ2;
            if (c0b == DEADC) {            // only lo side live: occ_a = 1/fa
                const float fa = fmaf(Ea, G[j], 1.f);
                occ2 = __builtin_amdgcn_cvt_pkrtz(__builtin_amdgcn_rcpf(fa), 0.f);
            } else if (c0a == DEADC) {     // only hi side live: occ_b = 1/fb
                const float fb = fmaf(Eb, G[j], 1.f);
                occ2 = __builtin_amdgcn_cvt_pkrtz(0.f, __builtin_amdgcn_rcpf(fb));
            } else {                       // both live: shared rcp
                const float fa = fmaf(Ea, G[j], 1.f);
                const float fb = fmaf(Eb, G[j], 1.f);
                const float rr = __builtin_amdgcn_rcpf(fa * fb);
                occ2 = __builtin_amdgcn_cvt_pkrtz(rr * fb, rr * fa);
            }
            const v2h c0h = {(__fp16)c0a, (__fp16)c0b};
            v2h t = coc2 + c0h;                          // v_pk_add_f16
            t = __builtin_elementwise_max(t, zero2);     // v_pk_max_f16
            t = __builtin_elementwise_min(t, onee2);     // v_pk_min_f16
            const v2h wh = t * occ2;                     // v_pk_mul_f16
            nr[j] = dot2acc(nr[j], wh, r2);
            ng[j] = dot2acc(ng[j], wh, g2);
            nb[j] = dot2acc(nb[j], wh, b2);
            dn[j] = dot2acc(dn[j], wh, one2);
        }
    }
}

__global__ __launch_bounds__(256, 4) void scatter_render_kernel(
    const float* __restrict__ x,      // (B,4,H,W)
    const float* __restrict__ lens,   // (B,1)
    float* __restrict__ out)          // (B,3,H,W)
{
    const int b   = blockIdx.z;
    const int bx0 = blockIdx.x * TSX;
    const int by0 = blockIdx.y * TSY;
    const int tx  = threadIdx.x;      // 0..15
    const int ty  = threadIdx.y;      // 0..15
    const int tid = ty * 16 + tx;

    const float scale = lens[b];
    const float* xb = x + (size_t)b * 4 * HW;

    // ---- stage window: all source-only math done once here (coc, Es);
    // pack {coc2,r2,g2,b2} into a swizzled uint4 slot + Es as bf16-RN pair.
    for (int p = tid; p < WINY * NPAIR; p += 256) {
        int wy = p / NPAIR;
        int sl = p - wy * NPAIR;
        int px = sl * 2;
        int gy = by0 - RAD + wy;  gy = min(max(gy, 0), IMG_H - 1);
        int g0 = bx0 - RAD + px;      g0 = min(max(g0, 0), IMG_W - 1);
        int g1 = bx0 - RAD + px + 1;  g1 = min(max(g1, 0), IMG_W - 1);
        int ba = gy * IMG_W + g0;
        int bb = gy * IMG_W + g1;
        float r0 = xb[ba],          r1 = xb[bb];
        float q0 = xb[ba + HW],     q1 = xb[bb + HW];
        float s0 = xb[ba + 2 * HW], s1 = xb[bb + 2 * HW];
        float d0 = xb[ba + 3 * HW], d1 = xb[bb + 3 * HW];
        uint4 q;
        v2h h;
        h = __builtin_amdgcn_cvt_pkrtz(scale * fabsf(d0), scale * fabsf(d1));
        q.x = *reinterpret_cast<unsigned*>(&h);
        h = __builtin_amdgcn_cvt_pkrtz(r0, r1);
        q.y = *reinterpret_cast<unsigned*>(&h);
        h = __builtin_amdgcn_cvt_pkrtz(q0, q1);
        q.z = *reinterpret_cast<unsigned*>(&h);
        h = __builtin_amdgcn_cvt_pkrtz(s0, s1);
        q.w = *reinterpret_cast<unsigned*>(&h);
        pk[wy * PKS + pswz(sl)] = q;
        // Es pair as round-to-nearest bf16 halves of one u32
        float Ea = __builtin_amdgcn_exp2f(C4L2 * d0);
        float Eb = __builtin_amdgcn_exp2f(C4L2 * d1);
        unsigned ua = (__float_as_uint(Ea) + 0x8000u) >> 16;
        unsigned ub = (__float_as_uint(Eb) + 0x8000u) & 0xffff0000u;
        es[wy * ESS + sl] = ua | ub;
    }
    __syncthreads();

    // per-dest occlusion gate: G_j = 1/Es(dest_j) from the SAME stored bf16
    // value dest reads as source -> self-occlusion exactly 0.5, den >= 0.25.
    const int x8 = 8 * tx;
    float G[8];
#pragma unroll
    for (int j = 0; j < 8; ++j) {
        const int cc = x8 + j + RAD;
        const unsigned ue = es[(ty + RAD) * ESS + (cc >> 1)];
        const float esd = (cc & 1) ? __uint_as_float(ue & 0xffff0000u)
                                   : __uint_as_float(ue << 16);
        G[j] = __builtin_amdgcn_rcpf(esd);
    }
    v2h one2; one2.x = (__fp16)1.f; one2.y = (__fp16)1.f;

    float nr[8] = {0.f, 0.f, 0.f, 0.f, 0.f, 0.f, 0.f, 0.f};
    float ng[8] = {0.f, 0.f, 0.f, 0.f, 0.f, 0.f, 0.f, 0.f};
    float nb[8] = {0.f, 0.f, 0.f, 0.f, 0.f, 0.f, 0.f, 0.f};
    float dn[8] = {0.f, 0.f, 0.f, 0.f, 0.f, 0.f, 0.f, 0.f};

    const int tx4 = 4 * tx;
    // mirrored row pairs share |dy| -> c0 compile-time; runtime 2-trip loops
    // keep live ranges bounded (R1's full unroll spilled).
#pragma unroll 1
    for (int t = 0; t < 2; ++t)
        do_row<5, 3, 7>(ty + t * 10, tx4, G, one2, nr, ng, nb, dn);
#pragma unroll 1
    for (int t = 0; t < 2; ++t)
        do_row<4, 2, 8>(ty + 1 + t * 8, tx4, G, one2, nr, ng, nb, dn);
#pragma unroll 1
    for (int t = 0; t < 2; ++t)
        do_row<3, 1, 9>(ty + 2 + t * 6, tx4, G, one2, nr, ng, nb, dn);
#pragma unroll 1
    for (int t = 0; t < 2; ++t)
        do_row<2, 0, 10>(ty + 3 + t * 4, tx4, G, one2, nr, ng, nb, dn);
#pragma unroll 1
    for (int t = 0; t < 2; ++t)
        do_row<1, 0, 10>(ty + 4 + t * 2, tx4, G, one2, nr, ng, nb, dn);
    do_row<0, 0, 10>(ty + 5, tx4, G, one2, nr, ng, nb, dn);

    // epilogue: 8 consecutive pixels -> 2x float4 stores per channel
    const size_t obase = (size_t)b * 3 * HW + (size_t)(by0 + ty) * IMG_W + (bx0 + x8);

    float inv[8];
#pragma unroll
    for (int j = 0; j < 8; ++j)
        inv[j] = __builtin_amdgcn_rcpf(dn[j] + 1e-8f);

#pragma unroll
    for (int h = 0; h < 2; ++h) {
        const int o4 = 4 * h;
        float4 o;
        o.x = nr[o4+0]*inv[o4+0]; o.y = nr[o4+1]*inv[o4+1];
        o.z = nr[o4+2]*inv[o4+2]; o.w = nr[o4+3]*inv[o4+3];
        *reinterpret_cast<float4*>(&out[obase + o4]) = o;
        o.x = ng[o4+0]*inv[o4+0]; o.y = ng[o4+1]*inv[o4+1];
        o.z = ng[o4+2]*inv[o4+2]; o.w = ng[o4+3]*inv[o4+3];
        *reinterpret_cast<float4*>(&out[obase + HW + o4]) = o;
        o.x = nb[o4+0]*inv[o4+0]; o.y = nb[o4+1]*inv[o4+1];
        o.z = nb[o4+2]*inv[o4+2]; o.w = nb[o4+3]*inv[o4+3];
        *reinterpret_cast<float4*>(&out[obase + 2 * HW + o4]) = o;
    }
}

extern "C" void kernel_launch(void* const* d_in, const int* in_sizes, int n_in,
                              void* d_out, int out_size, void* d_ws, size_t ws_size,
                              hipStream_t stream) {
    const float* x    = (const float*)d_in[0];
    const float* lens = (const float*)d_in[1];
    float* out        = (float*)d_out;

    const int B = in_sizes[1];  // lens_effects has B elements

    dim3 block(16, 16, 1);
    dim3 grid(IMG_W / TSX, IMG_H / TSY, B);
    scatter_render_kernel<<<grid, block, 0, stream>>>(x, lens, out);
}